// Round 7
// baseline (1418.062 us; speedup 1.0000x reference)
//
#include <hip/hip_runtime.h>
#include <hip/hip_bf16.h>

#define D 128        // EMBED == LAYER == 128
#define BSHIFT 7     // 128 users per bucket
#define BUSERS (1 << BSHIFT)
#define NBLK 256     // blocks for hist/scatter passes

// round-to-nearest f32 -> bf16 bits
__device__ __forceinline__ unsigned int bf16rn(float f) {
  unsigned int u = __float_as_uint(f);
  return (u + 0x7fffu + ((u >> 16) & 1u)) >> 16;
}

// ---------------------------------------------------------------------------
// Kernel 1: P = item_emb @ W  — register-tiled SGEMM, bf16 output.
// ---------------------------------------------------------------------------
__global__ __launch_bounds__(256) void pw_kernel(
    const float* __restrict__ emb, const float* __restrict__ W,
    unsigned short* __restrict__ Pb, int n_items) {
  __shared__ float Al[128][132];
  __shared__ float Wl[128][128];
  const int tid = threadIdx.x;
  const int m0 = blockIdx.x * 128;

  {
    const float4* W4 = reinterpret_cast<const float4*>(W);
    float4* Wl4 = reinterpret_cast<float4*>(&Wl[0][0]);
#pragma unroll
    for (int i = 0; i < 16; ++i) Wl4[tid + 256 * i] = W4[tid + 256 * i];
  }
  {
    const float4* E4 = reinterpret_cast<const float4*>(emb);
#pragma unroll
    for (int i = 0; i < 16; ++i) {
      const int f = tid + 256 * i;
      const int row = f >> 5;
      const int c4 = (f & 31) * 4;
      const int r = m0 + row;
      float4 v = {0.f, 0.f, 0.f, 0.f};
      if (r < n_items) v = E4[(size_t)r * 32 + (f & 31)];
      *reinterpret_cast<float4*>(&Al[row][c4]) = v;
    }
  }
  __syncthreads();

  const int tx = tid & 15;
  const int ty = tid >> 4;
  const int c0 = tx * 8;
  const int r0 = ty * 8;

  float acc[8][8];
#pragma unroll
  for (int i = 0; i < 8; ++i)
#pragma unroll
    for (int j = 0; j < 8; ++j) acc[i][j] = 0.f;

  for (int k = 0; k < D; ++k) {
    float a[8];
#pragma unroll
    for (int i = 0; i < 8; ++i) a[i] = Al[r0 + i][k];
    const float4 w0 = *reinterpret_cast<const float4*>(&Wl[k][c0]);
    const float4 w1 = *reinterpret_cast<const float4*>(&Wl[k][c0 + 4]);
#pragma unroll
    for (int i = 0; i < 8; ++i) {
      acc[i][0] += a[i] * w0.x; acc[i][1] += a[i] * w0.y;
      acc[i][2] += a[i] * w0.z; acc[i][3] += a[i] * w0.w;
      acc[i][4] += a[i] * w1.x; acc[i][5] += a[i] * w1.y;
      acc[i][6] += a[i] * w1.z; acc[i][7] += a[i] * w1.w;
    }
  }

#pragma unroll
  for (int i = 0; i < 8; ++i) {
    const int r = m0 + r0 + i;
    if (r < n_items) {
      uint4 o;
      o.x = bf16rn(acc[i][0]) | (bf16rn(acc[i][1]) << 16);
      o.y = bf16rn(acc[i][2]) | (bf16rn(acc[i][3]) << 16);
      o.z = bf16rn(acc[i][4]) | (bf16rn(acc[i][5]) << 16);
      o.w = bf16rn(acc[i][6]) | (bf16rn(acc[i][7]) << 16);
      *reinterpret_cast<uint4*>(reinterpret_cast<unsigned int*>(Pb) +
                                (size_t)r * 64 + tx * 4) = o;
    }
  }
}

// ---------------------------------------------------------------------------
// Kernel 2: per-block bucket histogram (LDS atomics only).
// bcount layout: [bucket][block]  (bucket-major) for the scan.
// ---------------------------------------------------------------------------
__global__ __launch_bounds__(256) void hist2_kernel(
    const int* __restrict__ rows, int* __restrict__ bcount, int n_edges,
    int epb, int nbuck) {
  __shared__ int h[1024];
  const int tid = threadIdx.x;
  for (int b = tid; b < nbuck; b += 256) h[b] = 0;
  __syncthreads();
  const int e0 = blockIdx.x * epb;
  const int e1 = (e0 + epb < n_edges) ? e0 + epb : n_edges;
  for (int e = e0 + tid; e < e1; e += 256) atomicAdd(&h[rows[e] >> BSHIFT], 1);
  __syncthreads();
  for (int b = tid; b < nbuck; b += 256)
    bcount[(size_t)b * NBLK + blockIdx.x] = h[b];
}

// ---------------------------------------------------------------------------
// Exclusive scan over bcount (nbuck*NBLK entries) -> base.
// ---------------------------------------------------------------------------
__global__ __launch_bounds__(1024) void blocksum_kernel(
    const int* __restrict__ in, int* __restrict__ partials, int n) {
  __shared__ int lds[1024];
  const int tid = threadIdx.x;
  const int i = blockIdx.x * 1024 + tid;
  lds[tid] = (i < n) ? in[i] : 0;
  __syncthreads();
  for (int s = 512; s > 0; s >>= 1) {
    if (tid < s) lds[tid] += lds[tid + s];
    __syncthreads();
  }
  if (tid == 0) partials[blockIdx.x] = lds[0];
}

__global__ __launch_bounds__(1024) void scanpart_kernel(
    const int* __restrict__ partials, int* __restrict__ blockoff, int nb) {
  __shared__ int lds[1024];
  const int tid = threadIdx.x;
  const int x = (tid < nb) ? partials[tid] : 0;
  lds[tid] = x;
  __syncthreads();
  for (int s = 1; s < 1024; s <<= 1) {
    const int y = (tid >= s) ? lds[tid - s] : 0;
    __syncthreads();
    lds[tid] += y;
    __syncthreads();
  }
  if (tid < nb) blockoff[tid] = lds[tid] - x;
}

__global__ __launch_bounds__(1024) void localscan_kernel(
    const int* __restrict__ in, const int* __restrict__ blockoff,
    int* __restrict__ base, int n) {
  __shared__ int lds[1024];
  const int tid = threadIdx.x;
  const int i = blockIdx.x * 1024 + tid;
  const int x = (i < n) ? in[i] : 0;
  lds[tid] = x;
  __syncthreads();
  for (int s = 1; s < 1024; s <<= 1) {
    const int y = (tid >= s) ? lds[tid - s] : 0;
    __syncthreads();
    lds[tid] += y;
    __syncthreads();
  }
  if (i < n) base[i] = blockoff[blockIdx.x] + lds[tid] - x;
}

// ---------------------------------------------------------------------------
// Kernel 3: scatter pass — positions from LDS cursors seeded by scanned base.
// No global atomics. sedge[pos] = {(rlocal<<16)|col, val_bits}.
// ---------------------------------------------------------------------------
__global__ __launch_bounds__(256) void scatter2_kernel(
    const int* __restrict__ rows, const int* __restrict__ cols,
    const float* __restrict__ vals, const int* __restrict__ base,
    int2* __restrict__ sedge, int n_edges, int epb, int nbuck) {
  __shared__ int cur[1024];
  const int tid = threadIdx.x;
  for (int b = tid; b < nbuck; b += 256)
    cur[b] = base[(size_t)b * NBLK + blockIdx.x];
  __syncthreads();
  const int e0 = blockIdx.x * epb;
  const int e1 = (e0 + epb < n_edges) ? e0 + epb : n_edges;
  for (int e = e0 + tid; e < e1; e += 256) {
    const int r = rows[e];
    const int pos = atomicAdd(&cur[r >> BSHIFT], 1);
    sedge[pos] =
        make_int2(((r & (BUSERS - 1)) << 16) | cols[e], __float_as_int(vals[e]));
  }
}

// ---------------------------------------------------------------------------
// Kernel 4: fused bucket gather. One block per bucket; accumulate edges into
// a 64 KB LDS tile via ds_add_f32, scale by nj, coalesced row writes.
// ---------------------------------------------------------------------------
__global__ __launch_bounds__(512) void bucket_gather_kernel(
    const unsigned int* __restrict__ Pb,  // bf16 pairs, 64 uints per row
    const int* __restrict__ base, const int2* __restrict__ sedge,
    const float* __restrict__ nj, float* __restrict__ out, int n_users,
    int n_edges, int nbuck) {
  __shared__ float acc[BUSERS][D];  // 64 KB
  const int tid = threadIdx.x;
  const int b = blockIdx.x;
  const int u0 = b << BSHIFT;

  // zero the tile: 4096 float4 / 512 threads = 8 each
  {
    float4* a4 = reinterpret_cast<float4*>(&acc[0][0]);
    const float4 z = {0.f, 0.f, 0.f, 0.f};
#pragma unroll
    for (int i = 0; i < 8; ++i) a4[tid + 512 * i] = z;
  }
  __syncthreads();

  const int beg = base[(size_t)b * NBLK];
  const int end = (b + 1 < nbuck) ? base[(size_t)(b + 1) * NBLK] : n_edges;
  const int group = tid >> 5;  // 16 half-wave groups
  const int lane = tid & 31;

  for (int j = beg + group; j < end; j += 16) {
    const int2 p = sedge[j];
    const int r = ((unsigned int)p.x) >> 16;
    const int c = p.x & 0xffff;
    const float v = __int_as_float(p.y);
    const uint2 pv =
        *reinterpret_cast<const uint2*>(Pb + (size_t)c * 64 + lane * 2);
    atomicAdd(&acc[r][lane * 4 + 0], v * __uint_as_float(pv.x << 16));
    atomicAdd(&acc[r][lane * 4 + 1], v * __uint_as_float(pv.x & 0xffff0000u));
    atomicAdd(&acc[r][lane * 4 + 2], v * __uint_as_float(pv.y << 16));
    atomicAdd(&acc[r][lane * 4 + 3], v * __uint_as_float(pv.y & 0xffff0000u));
  }
  __syncthreads();

  // epilogue: 128 rows x 32 float4 = 4096 stores / 512 threads = 8 each
#pragma unroll
  for (int i = tid; i < BUSERS * 32; i += 512) {
    const int row = i >> 5;
    const int q = i & 31;
    const int u = u0 + row;
    if (u < n_users) {
      float4 a = *reinterpret_cast<float4*>(&acc[row][q * 4]);
      const float s = nj[u];
      a.x *= s; a.y *= s; a.z *= s; a.w *= s;
      *reinterpret_cast<float4*>(out + (size_t)u * D + q * 4) = a;
    }
  }
}

extern "C" void kernel_launch(void* const* d_in, const int* in_sizes, int n_in,
                              void* d_out, int out_size, void* d_ws,
                              size_t ws_size, hipStream_t stream) {
  const float* item_emb = (const float*)d_in[0];  // [n_items, 128]
  const float* user_nj  = (const float*)d_in[1];  // [n_users, 1]
  const float* weight   = (const float*)d_in[2];  // [128, 128]
  const float* adj_vals = (const float*)d_in[3];  // [E]
  const int*   adj_rows = (const int*)d_in[4];    // [E]
  const int*   adj_cols = (const int*)d_in[5];    // [E]

  const int n_items = in_sizes[0] / D;
  const int n_users = in_sizes[1];
  const int n_edges = in_sizes[3];
  float* out = (float*)d_out;

  const int nbuck = (n_users + BUSERS - 1) >> BSHIFT;  // 782
  const int epb = (n_edges + NBLK - 1) / NBLK;         // edges per pass block
  const int n_scan = nbuck * NBLK;                     // 200192
  const int nb_scan = (n_scan + 1023) / 1024;          // 196

  // ---- workspace layout (256B-aligned) ----
  auto align256 = [](size_t x) { return (x + 255) & ~(size_t)255; };
  char* ws = (char*)d_ws;
  size_t off = 0;
  unsigned short* Pb = (unsigned short*)(ws + off);
  off = align256(off + (size_t)n_items * D * 2);  // 12.8 MB
  int* bcount = (int*)(ws + off);  off = align256(off + (size_t)n_scan * 4);
  int* base = (int*)(ws + off);    off = align256(off + (size_t)n_scan * 4);
  int2* sedge = (int2*)(ws + off); off = align256(off + (size_t)n_edges * 8);
  int* partials = (int*)(ws + off); off = align256(off + (size_t)nb_scan * 4);
  int* blockoff = (int*)(ws + off); off = align256(off + (size_t)nb_scan * 4);

  // 1) P = item_emb @ W  (bf16 output)
  pw_kernel<<<(n_items + 127) / 128, 256, 0, stream>>>(item_emb, weight, Pb,
                                                       n_items);

  // 2) per-block bucket histograms (writes every cell -> no memset)
  hist2_kernel<<<NBLK, 256, 0, stream>>>(adj_rows, bcount, n_edges, epb,
                                         nbuck);

  // 3) exclusive scan of bcount -> base
  blocksum_kernel<<<nb_scan, 1024, 0, stream>>>(bcount, partials, n_scan);
  scanpart_kernel<<<1, 1024, 0, stream>>>(partials, blockoff, nb_scan);
  localscan_kernel<<<nb_scan, 1024, 0, stream>>>(bcount, blockoff, base,
                                                 n_scan);

  // 4) scatter edges into bucket-sorted order (no global atomics)
  scatter2_kernel<<<NBLK, 256, 0, stream>>>(adj_rows, adj_cols, adj_vals, base,
                                            sedge, n_edges, epb, nbuck);

  // 5) fused per-bucket gather + nj scale + store
  bucket_gather_kernel<<<nbuck, 512, 0, stream>>>(
      reinterpret_cast<const unsigned int*>(Pb), base, sedge, user_nj, out,
      n_users, n_edges, nbuck);
}

// Round 8
// 211.031 us; speedup vs baseline: 6.7197x; 6.7197x over previous
//
#include <hip/hip_runtime.h>
#include <hip/hip_bf16.h>

#define D 128        // EMBED == LAYER == 128
#define BSHIFT 7     // 128 users per bucket
#define BUSERS (1 << BSHIFT)
#define NBLK 256     // blocks for hist/scatter passes
#define CHUNK 2560   // edges staged per bucket-chunk (avg bucket ~2046)

// round-to-nearest f32 -> bf16 bits
__device__ __forceinline__ unsigned int bf16rn(float f) {
  unsigned int u = __float_as_uint(f);
  return (u + 0x7fffu + ((u >> 16) & 1u)) >> 16;
}

// ---------------------------------------------------------------------------
// Kernel 1: P = item_emb @ W  — register-tiled SGEMM, bf16 output.
// ---------------------------------------------------------------------------
__global__ __launch_bounds__(256) void pw_kernel(
    const float* __restrict__ emb, const float* __restrict__ W,
    unsigned short* __restrict__ Pb, int n_items) {
  __shared__ float Al[128][132];
  __shared__ float Wl[128][128];
  const int tid = threadIdx.x;
  const int m0 = blockIdx.x * 128;

  {
    const float4* W4 = reinterpret_cast<const float4*>(W);
    float4* Wl4 = reinterpret_cast<float4*>(&Wl[0][0]);
#pragma unroll
    for (int i = 0; i < 16; ++i) Wl4[tid + 256 * i] = W4[tid + 256 * i];
  }
  {
    const float4* E4 = reinterpret_cast<const float4*>(emb);
#pragma unroll
    for (int i = 0; i < 16; ++i) {
      const int f = tid + 256 * i;
      const int row = f >> 5;
      const int c4 = (f & 31) * 4;
      const int r = m0 + row;
      float4 v = {0.f, 0.f, 0.f, 0.f};
      if (r < n_items) v = E4[(size_t)r * 32 + (f & 31)];
      *reinterpret_cast<float4*>(&Al[row][c4]) = v;
    }
  }
  __syncthreads();

  const int tx = tid & 15;
  const int ty = tid >> 4;
  const int c0 = tx * 8;
  const int r0 = ty * 8;

  float acc[8][8];
#pragma unroll
  for (int i = 0; i < 8; ++i)
#pragma unroll
    for (int j = 0; j < 8; ++j) acc[i][j] = 0.f;

  for (int k = 0; k < D; ++k) {
    float a[8];
#pragma unroll
    for (int i = 0; i < 8; ++i) a[i] = Al[r0 + i][k];
    const float4 w0 = *reinterpret_cast<const float4*>(&Wl[k][c0]);
    const float4 w1 = *reinterpret_cast<const float4*>(&Wl[k][c0 + 4]);
#pragma unroll
    for (int i = 0; i < 8; ++i) {
      acc[i][0] += a[i] * w0.x; acc[i][1] += a[i] * w0.y;
      acc[i][2] += a[i] * w0.z; acc[i][3] += a[i] * w0.w;
      acc[i][4] += a[i] * w1.x; acc[i][5] += a[i] * w1.y;
      acc[i][6] += a[i] * w1.z; acc[i][7] += a[i] * w1.w;
    }
  }

#pragma unroll
  for (int i = 0; i < 8; ++i) {
    const int r = m0 + r0 + i;
    if (r < n_items) {
      uint4 o;
      o.x = bf16rn(acc[i][0]) | (bf16rn(acc[i][1]) << 16);
      o.y = bf16rn(acc[i][2]) | (bf16rn(acc[i][3]) << 16);
      o.z = bf16rn(acc[i][4]) | (bf16rn(acc[i][5]) << 16);
      o.w = bf16rn(acc[i][6]) | (bf16rn(acc[i][7]) << 16);
      *reinterpret_cast<uint4*>(reinterpret_cast<unsigned int*>(Pb) +
                                (size_t)r * 64 + tx * 4) = o;
    }
  }
}

// ---------------------------------------------------------------------------
// Kernel 2: per-block bucket histogram (LDS atomics only).
// bcount layout: [bucket][block]  (bucket-major) for the scan.
// ---------------------------------------------------------------------------
__global__ __launch_bounds__(256) void hist2_kernel(
    const int* __restrict__ rows, int* __restrict__ bcount, int n_edges,
    int epb, int nbuck) {
  __shared__ int h[1024];
  const int tid = threadIdx.x;
  for (int b = tid; b < nbuck; b += 256) h[b] = 0;
  __syncthreads();
  const int e0 = blockIdx.x * epb;
  const int e1 = (e0 + epb < n_edges) ? e0 + epb : n_edges;
  for (int e = e0 + tid; e < e1; e += 256) atomicAdd(&h[rows[e] >> BSHIFT], 1);
  __syncthreads();
  for (int b = tid; b < nbuck; b += 256)
    bcount[(size_t)b * NBLK + blockIdx.x] = h[b];
}

// ---------------------------------------------------------------------------
// Exclusive scan over bcount (nbuck*NBLK entries) -> base.
// ---------------------------------------------------------------------------
__global__ __launch_bounds__(1024) void blocksum_kernel(
    const int* __restrict__ in, int* __restrict__ partials, int n) {
  __shared__ int lds[1024];
  const int tid = threadIdx.x;
  const int i = blockIdx.x * 1024 + tid;
  lds[tid] = (i < n) ? in[i] : 0;
  __syncthreads();
  for (int s = 512; s > 0; s >>= 1) {
    if (tid < s) lds[tid] += lds[tid + s];
    __syncthreads();
  }
  if (tid == 0) partials[blockIdx.x] = lds[0];
}

__global__ __launch_bounds__(1024) void scanpart_kernel(
    const int* __restrict__ partials, int* __restrict__ blockoff, int nb) {
  __shared__ int lds[1024];
  const int tid = threadIdx.x;
  const int x = (tid < nb) ? partials[tid] : 0;
  lds[tid] = x;
  __syncthreads();
  for (int s = 1; s < 1024; s <<= 1) {
    const int y = (tid >= s) ? lds[tid - s] : 0;
    __syncthreads();
    lds[tid] += y;
    __syncthreads();
  }
  if (tid < nb) blockoff[tid] = lds[tid] - x;
}

__global__ __launch_bounds__(1024) void localscan_kernel(
    const int* __restrict__ in, const int* __restrict__ blockoff,
    int* __restrict__ base, int n) {
  __shared__ int lds[1024];
  const int tid = threadIdx.x;
  const int i = blockIdx.x * 1024 + tid;
  const int x = (i < n) ? in[i] : 0;
  lds[tid] = x;
  __syncthreads();
  for (int s = 1; s < 1024; s <<= 1) {
    const int y = (tid >= s) ? lds[tid - s] : 0;
    __syncthreads();
    lds[tid] += y;
    __syncthreads();
  }
  if (i < n) base[i] = blockoff[blockIdx.x] + lds[tid] - x;
}

// ---------------------------------------------------------------------------
// Kernel 3: scatter pass — positions from LDS cursors seeded by scanned base.
// No global atomics. sedge[pos] = {(rlocal<<16)|col, val_bits}.
// ---------------------------------------------------------------------------
__global__ __launch_bounds__(256) void scatter2_kernel(
    const int* __restrict__ rows, const int* __restrict__ cols,
    const float* __restrict__ vals, const int* __restrict__ base,
    int2* __restrict__ sedge, int n_edges, int epb, int nbuck) {
  __shared__ int cur[1024];
  const int tid = threadIdx.x;
  for (int b = tid; b < nbuck; b += 256)
    cur[b] = base[(size_t)b * NBLK + blockIdx.x];
  __syncthreads();
  const int e0 = blockIdx.x * epb;
  const int e1 = (e0 + epb < n_edges) ? e0 + epb : n_edges;
  for (int e = e0 + tid; e < e1; e += 256) {
    const int r = rows[e];
    const int pos = atomicAdd(&cur[r >> BSHIFT], 1);
    sedge[pos] =
        make_int2(((r & (BUSERS - 1)) << 16) | cols[e], __float_as_int(vals[e]));
  }
}

// ---------------------------------------------------------------------------
// Kernel 4: per-bucket LDS counting-sort + REGISTER accumulation (no atomics
// in the accumulate path). One block per bucket, 512 threads = 8 waves.
// Wave w owns local users w*16..w*16+15; lane owns 2 fp columns.
// ---------------------------------------------------------------------------
__global__ __launch_bounds__(512) void bucket_gather_kernel(
    const unsigned int* __restrict__ Pb,  // bf16 pairs, 64 uints per row
    const int* __restrict__ base, const int2* __restrict__ sedge,
    const float* __restrict__ nj, float* __restrict__ out, int n_users,
    int n_edges, int nbuck) {
  __shared__ int2 eraw[CHUNK];    // 20 KB
  __shared__ int2 esort[CHUNK];   // 20 KB
  __shared__ int cnt[BUSERS];     // counters, then cursors
  __shared__ int incl[BUSERS];    // inclusive scan (run ends)

  const int tid = threadIdx.x;
  const int b = blockIdx.x;
  const int u0 = b << BSHIFT;
  const int wave = tid >> 6;      // 0..7
  const int lane = tid & 63;

  const int beg = base[(size_t)b * NBLK];
  const int end = (b + 1 < nbuck) ? base[(size_t)(b + 1) * NBLK] : n_edges;

  float2 acc[16];
#pragma unroll
  for (int k = 0; k < 16; ++k) acc[k] = {0.f, 0.f};

  for (int cbeg = beg; cbeg < end; cbeg += CHUNK) {
    const int cnum = (cbeg + CHUNK < end) ? CHUNK : (end - cbeg);
    // zero counters
    for (int i = tid; i < BUSERS; i += 512) cnt[i] = 0;
    __syncthreads();
    // stage chunk in LDS + per-user count
    for (int i = tid; i < cnum; i += 512) {
      const int2 e = sedge[cbeg + i];
      eraw[i] = e;
      atomicAdd(&cnt[((unsigned int)e.x) >> 16], 1);
    }
    __syncthreads();
    // inclusive scan of the 128 counts
    if (tid < BUSERS) incl[tid] = cnt[tid];
    __syncthreads();
    for (int s = 1; s < BUSERS; s <<= 1) {
      int y = 0;
      if (tid < BUSERS && tid >= s) y = incl[tid - s];
      __syncthreads();
      if (tid < BUSERS) incl[tid] += y;
      __syncthreads();
    }
    // cursors = exclusive starts
    if (tid < BUSERS) cnt[tid] = incl[tid] - cnt[tid];
    __syncthreads();
    // in-LDS scatter to user-sorted order
    for (int i = tid; i < cnum; i += 512) {
      const int2 e = eraw[i];
      const int pos = atomicAdd(&cnt[((unsigned int)e.x) >> 16], 1);
      esort[pos] = e;
    }
    __syncthreads();
    // register accumulate: wave-uniform runs, 2-wide unrolled loads
#pragma unroll
    for (int k = 0; k < 16; ++k) {
      const int ul = wave * 16 + k;
      const int s = (ul == 0) ? 0 : incl[ul - 1];
      const int t = incl[ul];
      int j = s;
      for (; j + 1 < t; j += 2) {
        const int2 e0 = esort[j];
        const int2 e1 = esort[j + 1];
        const unsigned int p0 = Pb[(size_t)(e0.x & 0xffff) * 64 + lane];
        const unsigned int p1 = Pb[(size_t)(e1.x & 0xffff) * 64 + lane];
        const float v0 = __int_as_float(e0.y);
        const float v1 = __int_as_float(e1.y);
        acc[k].x += v0 * __uint_as_float(p0 << 16);
        acc[k].y += v0 * __uint_as_float(p0 & 0xffff0000u);
        acc[k].x += v1 * __uint_as_float(p1 << 16);
        acc[k].y += v1 * __uint_as_float(p1 & 0xffff0000u);
      }
      if (j < t) {
        const int2 e0 = esort[j];
        const unsigned int p0 = Pb[(size_t)(e0.x & 0xffff) * 64 + lane];
        const float v0 = __int_as_float(e0.y);
        acc[k].x += v0 * __uint_as_float(p0 << 16);
        acc[k].y += v0 * __uint_as_float(p0 & 0xffff0000u);
      }
    }
    __syncthreads();  // protect LDS before next chunk
  }

  // epilogue: scale by nj, coalesced float2 stores
#pragma unroll
  for (int k = 0; k < 16; ++k) {
    const int u = u0 + wave * 16 + k;
    if (u < n_users) {
      const float s = nj[u];
      float2 a = acc[k];
      a.x *= s; a.y *= s;
      *reinterpret_cast<float2*>(out + (size_t)u * D + lane * 2) = a;
    }
  }
}

extern "C" void kernel_launch(void* const* d_in, const int* in_sizes, int n_in,
                              void* d_out, int out_size, void* d_ws,
                              size_t ws_size, hipStream_t stream) {
  const float* item_emb = (const float*)d_in[0];  // [n_items, 128]
  const float* user_nj  = (const float*)d_in[1];  // [n_users, 1]
  const float* weight   = (const float*)d_in[2];  // [128, 128]
  const float* adj_vals = (const float*)d_in[3];  // [E]
  const int*   adj_rows = (const int*)d_in[4];    // [E]
  const int*   adj_cols = (const int*)d_in[5];    // [E]

  const int n_items = in_sizes[0] / D;
  const int n_users = in_sizes[1];
  const int n_edges = in_sizes[3];
  float* out = (float*)d_out;

  const int nbuck = (n_users + BUSERS - 1) >> BSHIFT;  // 782
  const int epb = (n_edges + NBLK - 1) / NBLK;         // edges per pass block
  const int n_scan = nbuck * NBLK;                     // 200192
  const int nb_scan = (n_scan + 1023) / 1024;          // 196

  // ---- workspace layout (256B-aligned) ----
  auto align256 = [](size_t x) { return (x + 255) & ~(size_t)255; };
  char* ws = (char*)d_ws;
  size_t off = 0;
  unsigned short* Pb = (unsigned short*)(ws + off);
  off = align256(off + (size_t)n_items * D * 2);  // 12.8 MB
  int* bcount = (int*)(ws + off);  off = align256(off + (size_t)n_scan * 4);
  int* base = (int*)(ws + off);    off = align256(off + (size_t)n_scan * 4);
  int2* sedge = (int2*)(ws + off); off = align256(off + (size_t)n_edges * 8);
  int* partials = (int*)(ws + off); off = align256(off + (size_t)nb_scan * 4);
  int* blockoff = (int*)(ws + off); off = align256(off + (size_t)nb_scan * 4);

  // 1) P = item_emb @ W  (bf16 output)
  pw_kernel<<<(n_items + 127) / 128, 256, 0, stream>>>(item_emb, weight, Pb,
                                                       n_items);

  // 2) per-block bucket histograms (writes every cell -> no memset)
  hist2_kernel<<<NBLK, 256, 0, stream>>>(adj_rows, bcount, n_edges, epb,
                                         nbuck);

  // 3) exclusive scan of bcount -> base
  blocksum_kernel<<<nb_scan, 1024, 0, stream>>>(bcount, partials, n_scan);
  scanpart_kernel<<<1, 1024, 0, stream>>>(partials, blockoff, nb_scan);
  localscan_kernel<<<nb_scan, 1024, 0, stream>>>(bcount, blockoff, base,
                                                 n_scan);

  // 4) scatter edges into bucket-sorted order (no global atomics)
  scatter2_kernel<<<NBLK, 256, 0, stream>>>(adj_rows, adj_cols, adj_vals, base,
                                            sedge, n_edges, epb, nbuck);

  // 5) per-bucket LDS counting-sort + register gather + nj scale + store
  bucket_gather_kernel<<<nbuck, 512, 0, stream>>>(
      reinterpret_cast<const unsigned int*>(Pb), base, sedge, user_nj, out,
      n_users, n_edges, nbuck);
}

// Round 9
// 164.533 us; speedup vs baseline: 8.6187x; 1.2826x over previous
//
#include <hip/hip_runtime.h>
#include <hip/hip_bf16.h>

#define D 128        // EMBED == LAYER == 128
#define BSHIFT 7     // 128 users per bucket
#define BUSERS (1 << BSHIFT)
#define NBLK 256     // blocks for hist/scatter passes
#define CHUNK 2560   // edges staged per bucket-chunk (avg bucket ~2046)

// round-to-nearest f32 -> bf16 bits
__device__ __forceinline__ unsigned int bf16rn(float f) {
  unsigned int u = __float_as_uint(f);
  return (u + 0x7fffu + ((u >> 16) & 1u)) >> 16;
}

// ---------------------------------------------------------------------------
// Kernel 1: P = item_emb @ W  — register-tiled SGEMM, bf16 output.
// ---------------------------------------------------------------------------
__global__ __launch_bounds__(256) void pw_kernel(
    const float* __restrict__ emb, const float* __restrict__ W,
    unsigned short* __restrict__ Pb, int n_items) {
  __shared__ float Al[128][132];
  __shared__ float Wl[128][128];
  const int tid = threadIdx.x;
  const int m0 = blockIdx.x * 128;

  {
    const float4* W4 = reinterpret_cast<const float4*>(W);
    float4* Wl4 = reinterpret_cast<float4*>(&Wl[0][0]);
#pragma unroll
    for (int i = 0; i < 16; ++i) Wl4[tid + 256 * i] = W4[tid + 256 * i];
  }
  {
    const float4* E4 = reinterpret_cast<const float4*>(emb);
#pragma unroll
    for (int i = 0; i < 16; ++i) {
      const int f = tid + 256 * i;
      const int row = f >> 5;
      const int c4 = (f & 31) * 4;
      const int r = m0 + row;
      float4 v = {0.f, 0.f, 0.f, 0.f};
      if (r < n_items) v = E4[(size_t)r * 32 + (f & 31)];
      *reinterpret_cast<float4*>(&Al[row][c4]) = v;
    }
  }
  __syncthreads();

  const int tx = tid & 15;
  const int ty = tid >> 4;
  const int c0 = tx * 8;
  const int r0 = ty * 8;

  float acc[8][8];
#pragma unroll
  for (int i = 0; i < 8; ++i)
#pragma unroll
    for (int j = 0; j < 8; ++j) acc[i][j] = 0.f;

  for (int k = 0; k < D; ++k) {
    float a[8];
#pragma unroll
    for (int i = 0; i < 8; ++i) a[i] = Al[r0 + i][k];
    const float4 w0 = *reinterpret_cast<const float4*>(&Wl[k][c0]);
    const float4 w1 = *reinterpret_cast<const float4*>(&Wl[k][c0 + 4]);
#pragma unroll
    for (int i = 0; i < 8; ++i) {
      acc[i][0] += a[i] * w0.x; acc[i][1] += a[i] * w0.y;
      acc[i][2] += a[i] * w0.z; acc[i][3] += a[i] * w0.w;
      acc[i][4] += a[i] * w1.x; acc[i][5] += a[i] * w1.y;
      acc[i][6] += a[i] * w1.z; acc[i][7] += a[i] * w1.w;
    }
  }

#pragma unroll
  for (int i = 0; i < 8; ++i) {
    const int r = m0 + r0 + i;
    if (r < n_items) {
      uint4 o;
      o.x = bf16rn(acc[i][0]) | (bf16rn(acc[i][1]) << 16);
      o.y = bf16rn(acc[i][2]) | (bf16rn(acc[i][3]) << 16);
      o.z = bf16rn(acc[i][4]) | (bf16rn(acc[i][5]) << 16);
      o.w = bf16rn(acc[i][6]) | (bf16rn(acc[i][7]) << 16);
      *reinterpret_cast<uint4*>(reinterpret_cast<unsigned int*>(Pb) +
                                (size_t)r * 64 + tx * 4) = o;
    }
  }
}

// ---------------------------------------------------------------------------
// Kernel 2: per-block bucket histogram (LDS atomics only).
// bcount layout: [bucket][block]  (bucket-major) for the scan.
// ---------------------------------------------------------------------------
__global__ __launch_bounds__(256) void hist2_kernel(
    const int* __restrict__ rows, int* __restrict__ bcount, int n_edges,
    int epb, int nbuck) {
  __shared__ int h[1024];
  const int tid = threadIdx.x;
  for (int b = tid; b < nbuck; b += 256) h[b] = 0;
  __syncthreads();
  const int e0 = blockIdx.x * epb;
  const int e1 = (e0 + epb < n_edges) ? e0 + epb : n_edges;
  for (int e = e0 + tid; e < e1; e += 256) atomicAdd(&h[rows[e] >> BSHIFT], 1);
  __syncthreads();
  for (int b = tid; b < nbuck; b += 256)
    bcount[(size_t)b * NBLK + blockIdx.x] = h[b];
}

// ---------------------------------------------------------------------------
// Exclusive scan over bcount (nbuck*NBLK entries) -> base.
// ---------------------------------------------------------------------------
__global__ __launch_bounds__(1024) void blocksum_kernel(
    const int* __restrict__ in, int* __restrict__ partials, int n) {
  __shared__ int lds[1024];
  const int tid = threadIdx.x;
  const int i = blockIdx.x * 1024 + tid;
  lds[tid] = (i < n) ? in[i] : 0;
  __syncthreads();
  for (int s = 512; s > 0; s >>= 1) {
    if (tid < s) lds[tid] += lds[tid + s];
    __syncthreads();
  }
  if (tid == 0) partials[blockIdx.x] = lds[0];
}

__global__ __launch_bounds__(1024) void scanpart_kernel(
    const int* __restrict__ partials, int* __restrict__ blockoff, int nb) {
  __shared__ int lds[1024];
  const int tid = threadIdx.x;
  const int x = (tid < nb) ? partials[tid] : 0;
  lds[tid] = x;
  __syncthreads();
  for (int s = 1; s < 1024; s <<= 1) {
    const int y = (tid >= s) ? lds[tid - s] : 0;
    __syncthreads();
    lds[tid] += y;
    __syncthreads();
  }
  if (tid < nb) blockoff[tid] = lds[tid] - x;
}

__global__ __launch_bounds__(1024) void localscan_kernel(
    const int* __restrict__ in, const int* __restrict__ blockoff,
    int* __restrict__ base, int n) {
  __shared__ int lds[1024];
  const int tid = threadIdx.x;
  const int i = blockIdx.x * 1024 + tid;
  const int x = (i < n) ? in[i] : 0;
  lds[tid] = x;
  __syncthreads();
  for (int s = 1; s < 1024; s <<= 1) {
    const int y = (tid >= s) ? lds[tid - s] : 0;
    __syncthreads();
    lds[tid] += y;
    __syncthreads();
  }
  if (i < n) base[i] = blockoff[blockIdx.x] + lds[tid] - x;
}

// ---------------------------------------------------------------------------
// Kernel 3: scatter pass — positions from LDS cursors seeded by scanned base.
// No global atomics. sedge[pos] = {(rlocal<<16)|col, val_bits}.
// ---------------------------------------------------------------------------
__global__ __launch_bounds__(256) void scatter2_kernel(
    const int* __restrict__ rows, const int* __restrict__ cols,
    const float* __restrict__ vals, const int* __restrict__ base,
    int2* __restrict__ sedge, int n_edges, int epb, int nbuck) {
  __shared__ int cur[1024];
  const int tid = threadIdx.x;
  for (int b = tid; b < nbuck; b += 256)
    cur[b] = base[(size_t)b * NBLK + blockIdx.x];
  __syncthreads();
  const int e0 = blockIdx.x * epb;
  const int e1 = (e0 + epb < n_edges) ? e0 + epb : n_edges;
  for (int e = e0 + tid; e < e1; e += 256) {
    const int r = rows[e];
    const int pos = atomicAdd(&cur[r >> BSHIFT], 1);
    sedge[pos] =
        make_int2(((r & (BUSERS - 1)) << 16) | cols[e], __float_as_int(vals[e]));
  }
}

// ---------------------------------------------------------------------------
// Kernel 4: per-bucket LDS counting-sort + register accumulation.
// 512 threads = 16 half-waves; each half-wave owns 8 users (serial),
// 32 lanes own uint2 (4 bf16 cols) of the P row. 4-wide unrolled edge loop
// keeps 4 independent 256B gathers in flight per chain.
// ---------------------------------------------------------------------------
__global__ __launch_bounds__(512) void bucket_gather_kernel(
    const uint2* __restrict__ Pb2,  // bf16 quads, 32 uint2 per row
    const int* __restrict__ base, const int2* __restrict__ sedge,
    const float* __restrict__ nj, float* __restrict__ out, int n_users,
    int n_edges, int nbuck) {
  __shared__ int2 eraw[CHUNK];    // 20 KB
  __shared__ int2 esort[CHUNK];   // 20 KB
  __shared__ int cnt[BUSERS];
  __shared__ int incl[BUSERS];

  const int tid = threadIdx.x;
  const int b = blockIdx.x;
  const int u0 = b << BSHIFT;
  const int hw = tid >> 5;        // half-wave 0..15
  const int lane = tid & 31;

  const int beg = base[(size_t)b * NBLK];
  const int end = (b + 1 < nbuck) ? base[(size_t)(b + 1) * NBLK] : n_edges;

  float4 acc[8];
#pragma unroll
  for (int k = 0; k < 8; ++k) acc[k] = {0.f, 0.f, 0.f, 0.f};

  for (int cbeg = beg; cbeg < end; cbeg += CHUNK) {
    const int cnum = (cbeg + CHUNK < end) ? CHUNK : (end - cbeg);
    for (int i = tid; i < BUSERS; i += 512) cnt[i] = 0;
    __syncthreads();
    // stage chunk + per-user count
    for (int i = tid; i < cnum; i += 512) {
      const int2 e = sedge[cbeg + i];
      eraw[i] = e;
      atomicAdd(&cnt[((unsigned int)e.x) >> 16], 1);
    }
    __syncthreads();
    // inclusive scan of 128 counts
    if (tid < BUSERS) incl[tid] = cnt[tid];
    __syncthreads();
    for (int s = 1; s < BUSERS; s <<= 1) {
      int y = 0;
      if (tid < BUSERS && tid >= s) y = incl[tid - s];
      __syncthreads();
      if (tid < BUSERS) incl[tid] += y;
      __syncthreads();
    }
    if (tid < BUSERS) cnt[tid] = incl[tid] - cnt[tid];
    __syncthreads();
    // in-LDS scatter to user-sorted order
    for (int i = tid; i < cnum; i += 512) {
      const int2 e = eraw[i];
      const int pos = atomicAdd(&cnt[((unsigned int)e.x) >> 16], 1);
      esort[pos] = e;
    }
    __syncthreads();
    // register accumulate: half-wave per user, 4-wide unroll
#pragma unroll
    for (int k = 0; k < 8; ++k) {
      const int ul = hw * 8 + k;
      const int s = (ul == 0) ? 0 : incl[ul - 1];
      const int t = incl[ul];
      int j = s;
      for (; j + 3 < t; j += 4) {
        const int2 e0 = esort[j];
        const int2 e1 = esort[j + 1];
        const int2 e2 = esort[j + 2];
        const int2 e3 = esort[j + 3];
        const uint2 p0 = Pb2[(size_t)(e0.x & 0xffff) * 32 + lane];
        const uint2 p1 = Pb2[(size_t)(e1.x & 0xffff) * 32 + lane];
        const uint2 p2 = Pb2[(size_t)(e2.x & 0xffff) * 32 + lane];
        const uint2 p3 = Pb2[(size_t)(e3.x & 0xffff) * 32 + lane];
        const float v0 = __int_as_float(e0.y);
        const float v1 = __int_as_float(e1.y);
        const float v2 = __int_as_float(e2.y);
        const float v3 = __int_as_float(e3.y);
        acc[k].x += v0 * __uint_as_float(p0.x << 16);
        acc[k].y += v0 * __uint_as_float(p0.x & 0xffff0000u);
        acc[k].z += v0 * __uint_as_float(p0.y << 16);
        acc[k].w += v0 * __uint_as_float(p0.y & 0xffff0000u);
        acc[k].x += v1 * __uint_as_float(p1.x << 16);
        acc[k].y += v1 * __uint_as_float(p1.x & 0xffff0000u);
        acc[k].z += v1 * __uint_as_float(p1.y << 16);
        acc[k].w += v1 * __uint_as_float(p1.y & 0xffff0000u);
        acc[k].x += v2 * __uint_as_float(p2.x << 16);
        acc[k].y += v2 * __uint_as_float(p2.x & 0xffff0000u);
        acc[k].z += v2 * __uint_as_float(p2.y << 16);
        acc[k].w += v2 * __uint_as_float(p2.y & 0xffff0000u);
        acc[k].x += v3 * __uint_as_float(p3.x << 16);
        acc[k].y += v3 * __uint_as_float(p3.x & 0xffff0000u);
        acc[k].z += v3 * __uint_as_float(p3.y << 16);
        acc[k].w += v3 * __uint_as_float(p3.y & 0xffff0000u);
      }
      for (; j < t; ++j) {
        const int2 e0 = esort[j];
        const uint2 p0 = Pb2[(size_t)(e0.x & 0xffff) * 32 + lane];
        const float v0 = __int_as_float(e0.y);
        acc[k].x += v0 * __uint_as_float(p0.x << 16);
        acc[k].y += v0 * __uint_as_float(p0.x & 0xffff0000u);
        acc[k].z += v0 * __uint_as_float(p0.y << 16);
        acc[k].w += v0 * __uint_as_float(p0.y & 0xffff0000u);
      }
    }
    __syncthreads();  // protect LDS before next chunk
  }

  // epilogue: scale by nj, full-row coalesced float4 stores
#pragma unroll
  for (int k = 0; k < 8; ++k) {
    const int u = u0 + hw * 8 + k;
    if (u < n_users) {
      const float s = nj[u];
      float4 a = acc[k];
      a.x *= s; a.y *= s; a.z *= s; a.w *= s;
      *reinterpret_cast<float4*>(out + (size_t)u * D + lane * 4) = a;
    }
  }
}

extern "C" void kernel_launch(void* const* d_in, const int* in_sizes, int n_in,
                              void* d_out, int out_size, void* d_ws,
                              size_t ws_size, hipStream_t stream) {
  const float* item_emb = (const float*)d_in[0];  // [n_items, 128]
  const float* user_nj  = (const float*)d_in[1];  // [n_users, 1]
  const float* weight   = (const float*)d_in[2];  // [128, 128]
  const float* adj_vals = (const float*)d_in[3];  // [E]
  const int*   adj_rows = (const int*)d_in[4];    // [E]
  const int*   adj_cols = (const int*)d_in[5];    // [E]

  const int n_items = in_sizes[0] / D;
  const int n_users = in_sizes[1];
  const int n_edges = in_sizes[3];
  float* out = (float*)d_out;

  const int nbuck = (n_users + BUSERS - 1) >> BSHIFT;  // 782
  const int epb = (n_edges + NBLK - 1) / NBLK;         // edges per pass block
  const int n_scan = nbuck * NBLK;                     // 200192
  const int nb_scan = (n_scan + 1023) / 1024;          // 196

  // ---- workspace layout (256B-aligned) ----
  auto align256 = [](size_t x) { return (x + 255) & ~(size_t)255; };
  char* ws = (char*)d_ws;
  size_t off = 0;
  unsigned short* Pb = (unsigned short*)(ws + off);
  off = align256(off + (size_t)n_items * D * 2);  // 12.8 MB
  int* bcount = (int*)(ws + off);  off = align256(off + (size_t)n_scan * 4);
  int* base = (int*)(ws + off);    off = align256(off + (size_t)n_scan * 4);
  int2* sedge = (int2*)(ws + off); off = align256(off + (size_t)n_edges * 8);
  int* partials = (int*)(ws + off); off = align256(off + (size_t)nb_scan * 4);
  int* blockoff = (int*)(ws + off); off = align256(off + (size_t)nb_scan * 4);

  // 1) P = item_emb @ W  (bf16 output)
  pw_kernel<<<(n_items + 127) / 128, 256, 0, stream>>>(item_emb, weight, Pb,
                                                       n_items);

  // 2) per-block bucket histograms (writes every cell -> no memset)
  hist2_kernel<<<NBLK, 256, 0, stream>>>(adj_rows, bcount, n_edges, epb,
                                         nbuck);

  // 3) exclusive scan of bcount -> base
  blocksum_kernel<<<nb_scan, 1024, 0, stream>>>(bcount, partials, n_scan);
  scanpart_kernel<<<1, 1024, 0, stream>>>(partials, blockoff, nb_scan);
  localscan_kernel<<<nb_scan, 1024, 0, stream>>>(bcount, blockoff, base,
                                                 n_scan);

  // 4) scatter edges into bucket-sorted order (no global atomics)
  scatter2_kernel<<<NBLK, 256, 0, stream>>>(adj_rows, adj_cols, adj_vals, base,
                                            sedge, n_edges, epb, nbuck);

  // 5) per-bucket LDS counting-sort + register gather + nj scale + store
  bucket_gather_kernel<<<nbuck, 512, 0, stream>>>(
      reinterpret_cast<const uint2*>(Pb), base, sedge, user_nj, out,
      n_users, n_edges, nbuck);
}

// Round 10
// 151.189 us; speedup vs baseline: 9.3794x; 1.0883x over previous
//
#include <hip/hip_runtime.h>
#include <hip/hip_bf16.h>

#define D 128        // EMBED == LAYER == 128
#define BSHIFT 7     // 128 users per bucket
#define BUSERS (1 << BSHIFT)
#define NBLK 256     // blocks for hist/scatter passes
#define CHUNK 2560   // edges staged per bucket-chunk (avg bucket ~2046)
#define MROWS 64     // pw: item rows per block

typedef __attribute__((ext_vector_type(8))) short bf16x8;
typedef __attribute__((ext_vector_type(4))) float f32x4;

// round-to-nearest f32 -> bf16 bits
__device__ __forceinline__ unsigned int bf16rn(float f) {
  unsigned int u = __float_as_uint(f);
  return (u + 0x7fffu + ((u >> 16) & 1u)) >> 16;
}

// ---------------------------------------------------------------------------
// Kernel 1: P = item_emb @ W — MFMA bf16 GEMM.
// Block 256 thr (4 waves) x 64 item rows. W^T bf16 in LDS (32 KB, swizzled),
// A-tile bf16 in LDS (16 KB, swizzled). Each wave computes 16 rows x 128 cols
// via 8 col-steps x 4 k-steps of mfma_f32_16x16x32_bf16.
// A and B fragments use the SAME per-lane k-mapping (k = ks*32 + (lane>>4)*8
// + j), so the result is correct for any hardware k-bijection; C/D mapping is
// the m89-verified col=lane&15, row=(lane>>4)*4+reg.
// ---------------------------------------------------------------------------
__global__ __launch_bounds__(256) void pw_kernel(
    const float* __restrict__ emb, const float* __restrict__ W,
    unsigned short* __restrict__ Pb, int n_items) {
  __shared__ unsigned short Wt[128 * 128];   // Wt[c][k], swizzled, 32 KB
  __shared__ unsigned short At[MROWS * 128]; // At[r][k], swizzled, 16 KB
  const int tid = threadIdx.x;
  const int m0 = blockIdx.x * MROWS;

  // stage W^T: global read coalesced over c (i = k*128 + c)
  for (int i = tid; i < 128 * 128; i += 256) {
    const int k = i >> 7, c = i & 127;
    const unsigned short v = (unsigned short)bf16rn(W[i]);
    const int boff = c * 256 + ((2 * k) ^ ((c & 7) << 4));
    *reinterpret_cast<unsigned short*>(reinterpret_cast<char*>(Wt) + boff) = v;
  }
  // stage A tile: global read coalesced over k (i = r*128 + k)
  for (int i = tid; i < MROWS * 128; i += 256) {
    const int r = i >> 7, k = i & 127;
    const int gr = m0 + r;
    const float f = (gr < n_items) ? emb[(size_t)gr * 128 + k] : 0.f;
    const unsigned short v = (unsigned short)bf16rn(f);
    const int boff = r * 256 + ((2 * k) ^ ((r & 7) << 4));
    *reinterpret_cast<unsigned short*>(reinterpret_cast<char*>(At) + boff) = v;
  }
  __syncthreads();

  const int w = tid >> 6;       // wave 0..3 -> rows w*16..w*16+15
  const int lane = tid & 63;
  const int lr = lane & 15;
  const int lg = lane >> 4;

  // A fragments for this wave's 16 rows, all 4 k-steps
  bf16x8 a[4];
  {
    const int rloc = w * 16 + lr;
#pragma unroll
    for (int ks = 0; ks < 4; ++ks) {
      const int boff = rloc * 256 + (((ks * 64) + lg * 16) ^ ((lr & 7) << 4));
      a[ks] = *reinterpret_cast<const bf16x8*>(
          reinterpret_cast<const char*>(At) + boff);
    }
  }

  f32x4 acc[8];
#pragma unroll
  for (int cs = 0; cs < 8; ++cs) acc[cs] = {0.f, 0.f, 0.f, 0.f};

#pragma unroll
  for (int cs = 0; cs < 8; ++cs) {
    const int c = cs * 16 + lr;
#pragma unroll
    for (int ks = 0; ks < 4; ++ks) {
      const int boff = c * 256 + (((ks * 64) + lg * 16) ^ ((lr & 7) << 4));
      const bf16x8 b = *reinterpret_cast<const bf16x8*>(
          reinterpret_cast<const char*>(Wt) + boff);
      acc[cs] = __builtin_amdgcn_mfma_f32_16x16x32_bf16(a[ks], b, acc[cs],
                                                        0, 0, 0);
    }
  }

  // C-write: row = m0 + w*16 + lg*4 + reg, col = cs*16 + lr (bf16 stores,
  // 16 lanes of a group write 32 contiguous bytes per row)
#pragma unroll
  for (int cs = 0; cs < 8; ++cs) {
    const int c = cs * 16 + lr;
#pragma unroll
    for (int reg = 0; reg < 4; ++reg) {
      const int r = m0 + w * 16 + lg * 4 + reg;
      if (r < n_items)
        Pb[(size_t)r * 128 + c] = (unsigned short)bf16rn(acc[cs][reg]);
    }
  }
}

// ---------------------------------------------------------------------------
// Kernel 2: per-block bucket histogram (LDS atomics only).
// ---------------------------------------------------------------------------
__global__ __launch_bounds__(256) void hist2_kernel(
    const int* __restrict__ rows, int* __restrict__ bcount, int n_edges,
    int epb, int nbuck) {
  __shared__ int h[1024];
  const int tid = threadIdx.x;
  for (int b = tid; b < nbuck; b += 256) h[b] = 0;
  __syncthreads();
  const int e0 = blockIdx.x * epb;
  const int e1 = (e0 + epb < n_edges) ? e0 + epb : n_edges;
  for (int e = e0 + tid; e < e1; e += 256) atomicAdd(&h[rows[e] >> BSHIFT], 1);
  __syncthreads();
  for (int b = tid; b < nbuck; b += 256)
    bcount[(size_t)b * NBLK + blockIdx.x] = h[b];
}

// ---------------------------------------------------------------------------
// Exclusive scan over bcount (nbuck*NBLK entries) -> base.
// ---------------------------------------------------------------------------
__global__ __launch_bounds__(1024) void blocksum_kernel(
    const int* __restrict__ in, int* __restrict__ partials, int n) {
  __shared__ int lds[1024];
  const int tid = threadIdx.x;
  const int i = blockIdx.x * 1024 + tid;
  lds[tid] = (i < n) ? in[i] : 0;
  __syncthreads();
  for (int s = 512; s > 0; s >>= 1) {
    if (tid < s) lds[tid] += lds[tid + s];
    __syncthreads();
  }
  if (tid == 0) partials[blockIdx.x] = lds[0];
}

__global__ __launch_bounds__(1024) void scanpart_kernel(
    const int* __restrict__ partials, int* __restrict__ blockoff, int nb) {
  __shared__ int lds[1024];
  const int tid = threadIdx.x;
  const int x = (tid < nb) ? partials[tid] : 0;
  lds[tid] = x;
  __syncthreads();
  for (int s = 1; s < 1024; s <<= 1) {
    const int y = (tid >= s) ? lds[tid - s] : 0;
    __syncthreads();
    lds[tid] += y;
    __syncthreads();
  }
  if (tid < nb) blockoff[tid] = lds[tid] - x;
}

__global__ __launch_bounds__(1024) void localscan_kernel(
    const int* __restrict__ in, const int* __restrict__ blockoff,
    int* __restrict__ base, int n) {
  __shared__ int lds[1024];
  const int tid = threadIdx.x;
  const int i = blockIdx.x * 1024 + tid;
  const int x = (i < n) ? in[i] : 0;
  lds[tid] = x;
  __syncthreads();
  for (int s = 1; s < 1024; s <<= 1) {
    const int y = (tid >= s) ? lds[tid - s] : 0;
    __syncthreads();
    lds[tid] += y;
    __syncthreads();
  }
  if (i < n) base[i] = blockoff[blockIdx.x] + lds[tid] - x;
}

// ---------------------------------------------------------------------------
// Kernel 3: scatter pass — LDS cursors seeded by scanned base.
// ---------------------------------------------------------------------------
__global__ __launch_bounds__(256) void scatter2_kernel(
    const int* __restrict__ rows, const int* __restrict__ cols,
    const float* __restrict__ vals, const int* __restrict__ base,
    int2* __restrict__ sedge, int n_edges, int epb, int nbuck) {
  __shared__ int cur[1024];
  const int tid = threadIdx.x;
  for (int b = tid; b < nbuck; b += 256)
    cur[b] = base[(size_t)b * NBLK + blockIdx.x];
  __syncthreads();
  const int e0 = blockIdx.x * epb;
  const int e1 = (e0 + epb < n_edges) ? e0 + epb : n_edges;
  for (int e = e0 + tid; e < e1; e += 256) {
    const int r = rows[e];
    const int pos = atomicAdd(&cur[r >> BSHIFT], 1);
    sedge[pos] =
        make_int2(((r & (BUSERS - 1)) << 16) | cols[e], __float_as_int(vals[e]));
  }
}

// ---------------------------------------------------------------------------
// Kernel 4: per-bucket LDS counting-sort + register accumulation.
// Half-wave per user (32 lanes x uint2 = 4 bf16 cols each); 8-wide unrolled
// edge loop keeps 8 independent 256B gathers in flight per chain.
// ---------------------------------------------------------------------------
__global__ __launch_bounds__(512) void bucket_gather_kernel(
    const uint2* __restrict__ Pb2,  // bf16 quads, 32 uint2 per row
    const int* __restrict__ base, const int2* __restrict__ sedge,
    const float* __restrict__ nj, float* __restrict__ out, int n_users,
    int n_edges, int nbuck) {
  __shared__ int2 eraw[CHUNK];    // 20 KB
  __shared__ int2 esort[CHUNK];   // 20 KB
  __shared__ int cnt[BUSERS];
  __shared__ int incl[BUSERS];

  const int tid = threadIdx.x;
  const int b = blockIdx.x;
  const int u0 = b << BSHIFT;
  const int hw = tid >> 5;        // half-wave 0..15
  const int lane = tid & 31;

  const int beg = base[(size_t)b * NBLK];
  const int end = (b + 1 < nbuck) ? base[(size_t)(b + 1) * NBLK] : n_edges;

  float4 acc[8];
#pragma unroll
  for (int k = 0; k < 8; ++k) acc[k] = {0.f, 0.f, 0.f, 0.f};

  for (int cbeg = beg; cbeg < end; cbeg += CHUNK) {
    const int cnum = (cbeg + CHUNK < end) ? CHUNK : (end - cbeg);
    for (int i = tid; i < BUSERS; i += 512) cnt[i] = 0;
    __syncthreads();
    for (int i = tid; i < cnum; i += 512) {
      const int2 e = sedge[cbeg + i];
      eraw[i] = e;
      atomicAdd(&cnt[((unsigned int)e.x) >> 16], 1);
    }
    __syncthreads();
    if (tid < BUSERS) incl[tid] = cnt[tid];
    __syncthreads();
    for (int s = 1; s < BUSERS; s <<= 1) {
      int y = 0;
      if (tid < BUSERS && tid >= s) y = incl[tid - s];
      __syncthreads();
      if (tid < BUSERS) incl[tid] += y;
      __syncthreads();
    }
    if (tid < BUSERS) cnt[tid] = incl[tid] - cnt[tid];
    __syncthreads();
    for (int i = tid; i < cnum; i += 512) {
      const int2 e = eraw[i];
      const int pos = atomicAdd(&cnt[((unsigned int)e.x) >> 16], 1);
      esort[pos] = e;
    }
    __syncthreads();
    // register accumulate: half-wave per user, 8-wide MLP
#pragma unroll
    for (int k = 0; k < 8; ++k) {
      const int ul = hw * 8 + k;
      const int s = (ul == 0) ? 0 : incl[ul - 1];
      const int t = incl[ul];
      int j = s;
      for (; j + 7 < t; j += 8) {
        int2 e[8];
        uint2 p[8];
#pragma unroll
        for (int q = 0; q < 8; ++q) e[q] = esort[j + q];
#pragma unroll
        for (int q = 0; q < 8; ++q)
          p[q] = Pb2[(size_t)(e[q].x & 0xffff) * 32 + lane];
#pragma unroll
        for (int q = 0; q < 8; ++q) {
          const float v = __int_as_float(e[q].y);
          acc[k].x += v * __uint_as_float(p[q].x << 16);
          acc[k].y += v * __uint_as_float(p[q].x & 0xffff0000u);
          acc[k].z += v * __uint_as_float(p[q].y << 16);
          acc[k].w += v * __uint_as_float(p[q].y & 0xffff0000u);
        }
      }
      for (; j < t; ++j) {
        const int2 e0 = esort[j];
        const uint2 p0 = Pb2[(size_t)(e0.x & 0xffff) * 32 + lane];
        const float v0 = __int_as_float(e0.y);
        acc[k].x += v0 * __uint_as_float(p0.x << 16);
        acc[k].y += v0 * __uint_as_float(p0.x & 0xffff0000u);
        acc[k].z += v0 * __uint_as_float(p0.y << 16);
        acc[k].w += v0 * __uint_as_float(p0.y & 0xffff0000u);
      }
    }
    __syncthreads();  // protect LDS before next chunk
  }

  // epilogue: scale by nj, full-row coalesced float4 stores
#pragma unroll
  for (int k = 0; k < 8; ++k) {
    const int u = u0 + hw * 8 + k;
    if (u < n_users) {
      const float s = nj[u];
      float4 a = acc[k];
      a.x *= s; a.y *= s; a.z *= s; a.w *= s;
      *reinterpret_cast<float4*>(out + (size_t)u * D + lane * 4) = a;
    }
  }
}

extern "C" void kernel_launch(void* const* d_in, const int* in_sizes, int n_in,
                              void* d_out, int out_size, void* d_ws,
                              size_t ws_size, hipStream_t stream) {
  const float* item_emb = (const float*)d_in[0];  // [n_items, 128]
  const float* user_nj  = (const float*)d_in[1];  // [n_users, 1]
  const float* weight   = (const float*)d_in[2];  // [128, 128]
  const float* adj_vals = (const float*)d_in[3];  // [E]
  const int*   adj_rows = (const int*)d_in[4];    // [E]
  const int*   adj_cols = (const int*)d_in[5];    // [E]

  const int n_items = in_sizes[0] / D;
  const int n_users = in_sizes[1];
  const int n_edges = in_sizes[3];
  float* out = (float*)d_out;

  const int nbuck = (n_users + BUSERS - 1) >> BSHIFT;  // 782
  const int epb = (n_edges + NBLK - 1) / NBLK;         // edges per pass block
  const int n_scan = nbuck * NBLK;                     // 200192
  const int nb_scan = (n_scan + 1023) / 1024;          // 196

  // ---- workspace layout (256B-aligned) ----
  auto align256 = [](size_t x) { return (x + 255) & ~(size_t)255; };
  char* ws = (char*)d_ws;
  size_t off = 0;
  unsigned short* Pb = (unsigned short*)(ws + off);
  off = align256(off + (size_t)n_items * D * 2);  // 12.8 MB
  int* bcount = (int*)(ws + off);  off = align256(off + (size_t)n_scan * 4);
  int* base = (int*)(ws + off);    off = align256(off + (size_t)n_scan * 4);
  int2* sedge = (int2*)(ws + off); off = align256(off + (size_t)n_edges * 8);
  int* partials = (int*)(ws + off); off = align256(off + (size_t)nb_scan * 4);
  int* blockoff = (int*)(ws + off); off = align256(off + (size_t)nb_scan * 4);

  // 1) P = item_emb @ W  (MFMA bf16, bf16 output)
  pw_kernel<<<(n_items + MROWS - 1) / MROWS, 256, 0, stream>>>(
      item_emb, weight, Pb, n_items);

  // 2) per-block bucket histograms (writes every cell -> no memset)
  hist2_kernel<<<NBLK, 256, 0, stream>>>(adj_rows, bcount, n_edges, epb,
                                         nbuck);

  // 3) exclusive scan of bcount -> base
  blocksum_kernel<<<nb_scan, 1024, 0, stream>>>(bcount, partials, n_scan);
  scanpart_kernel<<<1, 1024, 0, stream>>>(partials, blockoff, nb_scan);
  localscan_kernel<<<nb_scan, 1024, 0, stream>>>(bcount, blockoff, base,
                                                 n_scan);

  // 4) scatter edges into bucket-sorted order (no global atomics)
  scatter2_kernel<<<NBLK, 256, 0, stream>>>(adj_rows, adj_cols, adj_vals, base,
                                            sedge, n_edges, epb, nbuck);

  // 5) per-bucket LDS counting-sort + register gather + nj scale + store
  bucket_gather_kernel<<<nbuck, 512, 0, stream>>>(
      reinterpret_cast<const uint2*>(Pb), base, sedge, user_nj, out,
      n_users, n_edges, nbuck);
}